// Round 9
// baseline (1888.244 us; speedup 1.0000x reference)
//
#include <hip/hip_runtime.h>
#include <hip/hip_bf16.h>
#include <math.h>

#define N 8192
#define BATCH 2
#define NROWS (BATCH*N)

typedef float v2f __attribute__((ext_vector_type(2)));

static __device__ __forceinline__ float fsubr(float a, float b){ return __fadd_rn(a, -b); }
static __device__ __forceinline__ unsigned okey(float f){
  unsigned u = __float_as_uint(f);
  return (u & 0x80000000u) ? ~u : (u | 0x80000000u);
}
static __device__ __forceinline__ unsigned spread3(unsigned v){
  return (v & 1u) | ((v & 2u) << 2) | ((v & 4u) << 4) | ((v & 8u) << 6);
}

// ---------------- aux: transpose xyz + |p|^2 + masked-coord float4 image (pre-mask copy)
__global__ void aux_kernel(const float* __restrict__ xyz, float* __restrict__ xs, float* __restrict__ ys,
                           float* __restrict__ zs, float* __restrict__ sq, float4* __restrict__ mxyz){
  int i = blockIdx.x*256 + threadIdx.x;
  if (i < NROWS){
    float x = xyz[i*3+0], y = xyz[i*3+1], z = xyz[i*3+2];
    xs[i]=x; ys[i]=y; zs[i]=z;
    sq[i] = __fadd_rn(__fadd_rn(__fmul_rn(x,x),__fmul_rn(y,y)),__fmul_rn(z,z));
    mxyz[i] = make_float4(x, y, z, 0.0f);
  }
}

// ---------------- far_val = max(xyz) + 1.0f
__global__ void farval_kernel(const float* __restrict__ xyz, float* __restrict__ farval){
  __shared__ float lm[4];
  float m = -1e30f;
  for (int i = threadIdx.x; i < NROWS*3; i += 256) m = fmaxf(m, xyz[i]);
  for (int off = 32; off; off >>= 1) m = fmaxf(m, __shfl_down(m, off));
  if ((threadIdx.x & 63) == 0) lm[threadIdx.x >> 6] = m;
  __syncthreads();
  if (threadIdx.x == 0){
    float r = fmaxf(fmaxf(lm[0],lm[1]), fmaxf(lm[2],lm[3]));
    farval[0] = __fadd_rn(r, 1.0f);
  }
}

// ---------------- Q = xyz @ w1[:3] + feat @ w1[3:]  (per global row, 128 cols)
__global__ __launch_bounds__(128) void q_kernel(const float* __restrict__ xyz, const float* __restrict__ feat,
                                                const float* __restrict__ w1, float* __restrict__ Q){
  __shared__ float sx[16][3];
  __shared__ float sf[16][64];
  const int t = threadIdx.x;
  const int row0 = blockIdx.x * 16;
  for (int j = t; j < 1024; j += 128) sf[j>>6][j&63] = feat[(size_t)row0*64 + j];
  if (t < 48) sx[t/3][t%3] = xyz[(size_t)row0*3 + t];
  __syncthreads();
  float acc[16];
  #pragma unroll
  for (int r = 0; r < 16; ++r) acc[r] = 0.0f;
  for (int c = 0; c < 3; ++c){
    float wv = w1[c*128 + t];
    #pragma unroll
    for (int r = 0; r < 16; ++r) acc[r] = fmaf(sx[r][c], wv, acc[r]);
  }
  for (int c = 0; c < 64; ++c){
    float wv = w1[(3+c)*128 + t];
    #pragma unroll
    for (int r = 0; r < 16; ++r) acc[r] = fmaf(sf[r][c], wv, acc[r]);
  }
  #pragma unroll
  for (int r = 0; r < 16; ++r) Q[(size_t)(row0+r)*128 + t] = acc[r];
}

// ---------------- KNN: per row, exact 65 smallest (d2, idx), drop rank0 (self), store 64 cand
#define BINBASE 0xBA00
__global__ __launch_bounds__(512) void knn_kernel(const float* __restrict__ xs, const float* __restrict__ ys,
                                                  const float* __restrict__ zs, const float* __restrict__ sq,
                                                  int* __restrict__ cand){
#pragma clang fp contract(off)
  __shared__ unsigned fk[N];
  __shared__ unsigned hist[2048];
  __shared__ unsigned long long win[1024];
  __shared__ int scal[8];
  const int t = threadIdx.x;
  const int base_row = blockIdx.x * 32;           // 512 blocks x 32 rows
  const int b = base_row >> 13;
  const int n0 = base_row & (N-1);
  const int pbase = b * N;
  v2f px[8], py[8], pz[8], ps[8];
  #pragma unroll
  for (int k = 0; k < 8; ++k){
    int i0 = t + (2*k)*512, i1 = t + (2*k+1)*512;
    px[k].x = xs[pbase+i0]; px[k].y = xs[pbase+i1];
    py[k].x = ys[pbase+i0]; py[k].y = ys[pbase+i1];
    pz[k].x = zs[pbase+i0]; pz[k].y = zs[pbase+i1];
    ps[k].x = sq[pbase+i0]; ps[k].y = sq[pbase+i1];
  }
  for (int r = 0; r < 32; ++r){
    const int n = n0 + r;
    const float qx = xs[pbase+n], qy = ys[pbase+n], qz = zs[pbase+n], qs = sq[pbase+n];
    #pragma unroll
    for (int j = 0; j < 4; ++j) hist[t + j*512] = 0;
    __syncthreads();
    #pragma unroll
    for (int k = 0; k < 8; ++k){
      v2f dot = px[k]*qx + py[k]*qy + pz[k]*qz;       // ((mul+mul)+mul), rn, packable
      v2f dd  = (qs + ps[k]) - 2.0f*dot;              // 2*dot exact; one rounding on sub
      unsigned u0 = okey(dd.x), u1 = okey(dd.y);
      fk[t + (2*k)*512] = u0;
      fk[t + (2*k+1)*512] = u1;
      int bin0 = (int)(u0 >> 16) - BINBASE; bin0 = bin0 < 0 ? 0 : (bin0 > 2047 ? 2047 : bin0);
      int bin1 = (int)(u1 >> 16) - BINBASE; bin1 = bin1 < 0 ? 0 : (bin1 > 2047 ? 2047 : bin1);
      atomicAdd(&hist[bin0], 1u);
      atomicAdd(&hist[bin1], 1u);
    }
    __syncthreads();
    if (t < 64){
      unsigned s = 0;
      for (int k2 = 0; k2 < 32; ++k2) s += hist[t*32 + ((k2 + t) & 31)];   // rotated: conflict-free
      unsigned p = s;
      for (int off = 1; off < 64; off <<= 1){ unsigned v = (unsigned)__shfl_up((int)p, off); if (t >= off) p += v; }
      int excl = (int)(p - s);
      if (excl < 65 && (int)p >= 65){ scal[0] = t; scal[1] = excl; }
    }
    __syncthreads();
    {
      int g = scal[0];
      if (t < 32){
        unsigned s = hist[g*32 + t];
        unsigned p = s;
        for (int off = 1; off < 32; off <<= 1){ unsigned v = (unsigned)__shfl_up((int)p, off); if (t >= off) p += v; }
        int before = scal[1] + (int)(p - s);
        if (before < 65 && scal[1] + (int)p >= 65) scal[2] = g*32 + t;
      }
    }
    if (t == 0) scal[3] = 0;
    __syncthreads();
    int B1 = scal[2];
    unsigned limit = (B1 >= 2047) ? 0xFFFFFFFFu : ((unsigned)(BINBASE + B1 + 1) << 16);
    #pragma unroll
    for (int j = 0; j < 16; ++j){
      int i = t + j*512;
      unsigned u = fk[i];
      if (u < limit){
        int p = atomicAdd(&scal[3], 1);
        if (p < 1024) win[p] = ((unsigned long long)u << 32) | (unsigned)i;
      }
    }
    __syncthreads();
    int m = scal[3]; if (m > 1024) m = 1024;
    for (int e = t; e < m; e += 512){
      unsigned long long me = win[e];
      int rk = 0;
      for (int j2 = 0; j2 < m; ++j2) rk += (win[j2] < me) ? 1 : 0;
      if (rk >= 1 && rk < 65) cand[(size_t)(pbase + n)*64 + (rk-1)] = (int)(me & 0xFFFFFFFFull);
    }
    __syncthreads();
  }
}

// ---------------- scores + top16 + covariance/eigen curvature + feat_var  (one wave per row)
__global__ __launch_bounds__(256) void score_kernel(const float* __restrict__ xyz, const float* __restrict__ feat,
                                                    const float* __restrict__ Q, const float* __restrict__ b1,
                                                    const float* __restrict__ w2, const float* __restrict__ b2,
                                                    const int* __restrict__ cand,
                                                    float* __restrict__ curv, float* __restrict__ fv){
  __shared__ float4 sb14[32], sw24[32];
  __shared__ int ssel[4][16];
  __shared__ float sdx[4][16], sdy[4][16], sdz[4][16], snrm[4][16];
  const int t = threadIdx.x;
  if (t < 32) sb14[t] = ((const float4*)b1)[t];
  else if (t < 64) sw24[t-32] = ((const float4*)w2)[t-32];
  __syncthreads();
  const int w = t >> 6, lane = t & 63;
  const int row = blockIdx.x*4 + w;               // global row
  const int b = row >> 13;
  const int pbase = b * N;
  const int n = row & (N-1);
  const int ck = cand[(size_t)row*64 + lane];
  const float4* Qn4 = (const float4*)(Q + (size_t)row * 128);
  const float4* Qc4 = (const float4*)(Q + (size_t)(pbase + ck) * 128);
  const float ks = 0.70710678118654752440f;
  float acc = 0.0f;
  for (int c = 0; c < 32; ++c){
    float4 qc = Qc4[c], qn = Qn4[c], bb = sb14[c], ww = sw24[c];
    float p0 = (qc.x - qn.x) + bb.x;
    float g0 = 0.5f * p0 * (1.0f + erff(p0 * ks));
    acc += g0 * ww.x;
    float p1 = (qc.y - qn.y) + bb.y;
    float g1 = 0.5f * p1 * (1.0f + erff(p1 * ks));
    acc += g1 * ww.y;
    float p2 = (qc.z - qn.z) + bb.z;
    float g2 = 0.5f * p2 * (1.0f + erff(p2 * ks));
    acc += g2 * ww.z;
    float p3 = (qc.w - qn.w) + bb.w;
    float g3 = 0.5f * p3 * (1.0f + erff(p3 * ks));
    acc += g3 * ww.w;
  }
  float score = acc + b2[0];
  unsigned key = okey(score);
  int rk = 0;
  for (int j = 0; j < 64; ++j){
    unsigned kj = (unsigned)__shfl((int)key, j);
    rk += (kj > key || (kj == key && j < lane)) ? 1 : 0;
  }
  float cx = xyz[(size_t)(pbase+ck)*3+0], cy = xyz[(size_t)(pbase+ck)*3+1], cz = xyz[(size_t)(pbase+ck)*3+2];
  float qxv = xyz[(size_t)(pbase+n)*3+0], qyv = xyz[(size_t)(pbase+n)*3+1], qzv = xyz[(size_t)(pbase+n)*3+2];
  if (rk < 16){
    ssel[w][rk] = ck;
    sdx[w][rk] = fsubr(cx, qxv);
    sdy[w][rk] = fsubr(cy, qyv);
    sdz[w][rk] = fsubr(cz, qzv);
  }
  __syncthreads();
  if (lane < 16){
    int si = ssel[w][lane];
    const float4* fc4 = (const float4*)(feat + (size_t)(pbase+si)*64);
    const float4* fn4 = (const float4*)(feat + (size_t)(pbase+n)*64);
    double s = 0.0;
    for (int c = 0; c < 16; ++c){
      float4 a = fc4[c], bq = fn4[c];
      float d0 = fsubr(a.x, bq.x); s += (double)d0 * (double)d0;
      float d1 = fsubr(a.y, bq.y); s += (double)d1 * (double)d1;
      float d2 = fsubr(a.z, bq.z); s += (double)d2 * (double)d2;
      float d3 = fsubr(a.w, bq.w); s += (double)d3 * (double)d3;
    }
    snrm[w][lane] = sqrtf((float)s);
  }
  __syncthreads();
  if (lane == 0){
    double cxx=0, cxy=0, cxz=0, cyy=0, cyz=0, czz=0;
    for (int k2 = 0; k2 < 16; ++k2){
      double dx = (double)sdx[w][k2], dy = (double)sdy[w][k2], dz = (double)sdz[w][k2];
      cxx += dx*dx; cxy += dx*dy; cxz += dx*dz; cyy += dy*dy; cyz += dy*dz; czz += dz*dz;
    }
    float fxx = (float)(cxx/16.0), fxy = (float)(cxy/16.0), fxz = (float)(cxz/16.0);
    float fyy = (float)(cyy/16.0), fyz = (float)(cyz/16.0), fzz = (float)(czz/16.0);
    double a = fxx, bbv = fyy, c = fzz, d = fxy, e = fyz, f = fxz;
    double p1 = d*d + f*f + e*e;
    double e0, e1, e2v;
    if (p1 == 0.0){ e0 = a; e1 = bbv; e2v = c; }
    else {
      double q = (a + bbv + c) / 3.0;
      double aa = a - q, bq = bbv - q, cc = c - q;
      double p2 = aa*aa + bq*bq + cc*cc + 2.0*p1;
      double p = sqrt(p2 / 6.0);
      double inv = 1.0 / p;
      double bxx = aa*inv, byy = bq*inv, bzz = cc*inv, bxy = d*inv, bxz = f*inv, byz = e*inv;
      double detB = bxx*(byy*bzz - byz*byz) - bxy*(bxy*bzz - byz*bxz) + bxz*(bxy*byz - byy*bxz);
      double rr = 0.5 * detB;
      rr = fmin(1.0, fmax(-1.0, rr));
      double phi = acos(rr) / 3.0;
      e0 = q + 2.0*p*cos(phi);
      e2v = q + 2.0*p*cos(phi + 2.0943951023931953);
      e1 = 3.0*q - e0 - e2v;
    }
    double s0 = fabs(e0), s1 = fabs(e1), s2d = fabs(e2v), tt;
    if (s0 < s1){ tt=s0; s0=s1; s1=tt; }
    if (s1 < s2d){ tt=s1; s1=s2d; s2d=tt; }
    if (s0 < s1){ tt=s0; s0=s1; s1=tt; }
    float sv0 = (float)s0, sv1 = (float)s1, sv2 = (float)s2d;
    float l2f = __fmul_rn(sv0,sv0), l1f = __fmul_rn(sv1,sv1), l0f = __fmul_rn(sv2,sv2);
    float den = __fadd_rn(__fadd_rn(__fadd_rn(l0f, l1f), l2f), 1e-8f);
    curv[row] = l0f / den;
    double fs = 0.0;
    for (int k2 = 0; k2 < 16; ++k2) fs += (double)snrm[w][k2];
    fv[row] = (float)(fs / 16.0);
  }
}

// ---------------- per-batch znorm + importance
static __device__ __forceinline__ double blk_sum(double v, double* lds, int t){
  for (int off = 32; off; off >>= 1) v += __shfl_down(v, off);
  int w = t >> 6, lane = t & 63;
  if (lane == 0) lds[w] = v;
  __syncthreads();
  double r = (t < 16) ? lds[t] : 0.0;
  if (t < 64){ for (int off = 8; off; off >>= 1) r += __shfl_down(r, off); }
  if (t == 0) lds[0] = r;
  __syncthreads();
  double out = lds[0];
  __syncthreads();
  return out;
}

__global__ __launch_bounds__(1024) void stats_kernel(const float* __restrict__ curv, const float* __restrict__ fv,
                                                     float* __restrict__ imp){
  __shared__ double lds[16];
  const int t = threadIdx.x;
  const int base = blockIdx.x * N;
  double sc = 0, sf = 0;
  for (int j = 0; j < 8; ++j){ int i = t + j*1024; sc += (double)curv[base+i]; sf += (double)fv[base+i]; }
  double Sc = blk_sum(sc, lds, t);
  double Sf = blk_sum(sf, lds, t);
  double mc = Sc/8192.0, mf = Sf/8192.0;
  double vc = 0, vf = 0;
  for (int j = 0; j < 8; ++j){ int i = t + j*1024;
    double d1 = (double)curv[base+i] - mc; vc += d1*d1;
    double d2 = (double)fv[base+i]  - mf; vf += d2*d2; }
  double Vc = blk_sum(vc, lds, t);
  double Vf = blk_sum(vf, lds, t);
  float mcf = (float)mc, mff = (float)mf;
  float dc = __fadd_rn((float)sqrt(Vc/8191.0), 1e-8f);
  float df = __fadd_rn((float)sqrt(Vf/8191.0), 1e-8f);
  for (int j = 0; j < 8; ++j){ int i = t + j*1024;
    float zc = fsubr(curv[base+i], mcf) / dc;
    float zf = fsubr(fv[base+i],  mff) / df;
    imp[base+i] = __fadd_rn(zc, __fmul_rn(0.5f, zf));
  }
}

// ---------------- top-1024 importance (ordered) -> curv_idx + masked-coord scatter (far)
__global__ __launch_bounds__(1024) void topk_kernel(const float* __restrict__ imp, int* __restrict__ merged,
                                                    float4* __restrict__ mxyz, const float* __restrict__ farval){
  __shared__ unsigned dk[N];
  __shared__ unsigned hist[2048];
  __shared__ unsigned long long win[2048];
  __shared__ int scal[8];
  const int t = threadIdx.x;
  const int b = blockIdx.x;
  const int base = b * N;
  #pragma unroll
  for (int j = 0; j < 2; ++j) hist[t + j*1024] = 0;
  if (t == 0) scal[3] = 0;
  __syncthreads();
  for (int j = 0; j < 8; ++j){
    int i = t + j*1024;
    unsigned u = ~okey(imp[base+i]);   // ascending = descending importance
    dk[i] = u;
    atomicAdd(&hist[u >> 21], 1u);
  }
  __syncthreads();
  if (t < 64){
    unsigned s = 0;
    for (int k2 = 0; k2 < 32; ++k2) s += hist[t*32 + ((k2 + t) & 31)];
    unsigned p = s;
    for (int off = 1; off < 64; off <<= 1){ unsigned v = (unsigned)__shfl_up((int)p, off); if (t >= off) p += v; }
    int excl = (int)(p - s);
    if (excl < 1024 && (int)p >= 1024){ scal[0] = t; scal[1] = excl; }
  }
  __syncthreads();
  {
    int g = scal[0];
    if (t < 32){
      unsigned s = hist[g*32 + t];
      unsigned p = s;
      for (int off = 1; off < 32; off <<= 1){ unsigned v = (unsigned)__shfl_up((int)p, off); if (t >= off) p += v; }
      int before = scal[1] + (int)(p - s);
      if (before < 1024 && scal[1] + (int)p >= 1024) scal[2] = g*32 + t;
    }
  }
  __syncthreads();
  unsigned B1 = (unsigned)scal[2];
  unsigned limit = (B1 >= 2047u) ? 0xFFFFFFFFu : ((B1+1u) << 21);
  for (int j = 0; j < 8; ++j){
    int i = t + j*1024;
    unsigned u = dk[i];
    if (u < limit){
      int p = atomicAdd(&scal[3], 1);
      if (p < 2048) win[p] = ((unsigned long long)u << 13) | (unsigned)i;
    }
  }
  __syncthreads();
  int m = scal[3]; if (m > 2048) m = 2048;
  const float far = farval[0];
  for (int e = t; e < m; e += 1024){
    unsigned long long me = win[e];
    int rk = 0;
    for (int j2 = 0; j2 < m; ++j2) rk += (win[j2] < me) ? 1 : 0;
    if (rk < 1024){
      int idx = (int)(me & 0x1FFFull);
      merged[b*2048 + rk] = idx;
      mxyz[base + idx] = make_float4(far, far, far, 0.0f);
    }
  }
}

// ---------------- Morton counting sort of masked points -> psort (x,y,z, orig_idx bits)
__global__ __launch_bounds__(1024) void sort_kernel(const float4* __restrict__ mxyz, float4* __restrict__ psort){
  __shared__ unsigned hist[4096];
  __shared__ float r6[16][6];
  __shared__ float bounds[6];
  __shared__ unsigned wsum[16];
  const int t = threadIdx.x;
  const int b = blockIdx.x;
  const int base = b * N;
  const int lane = t & 63, wv = t >> 6;
  float4 p[8];
  #pragma unroll
  for (int j = 0; j < 8; ++j) p[j] = mxyz[base + t + j*1024];
  float mnx=p[0].x, mxx=p[0].x, mny=p[0].y, mxy=p[0].y, mnz=p[0].z, mxz=p[0].z;
  #pragma unroll
  for (int j = 1; j < 8; ++j){
    mnx=fminf(mnx,p[j].x); mxx=fmaxf(mxx,p[j].x);
    mny=fminf(mny,p[j].y); mxy=fmaxf(mxy,p[j].y);
    mnz=fminf(mnz,p[j].z); mxz=fmaxf(mxz,p[j].z);
  }
  #pragma unroll
  for (int off = 32; off; off >>= 1){
    mnx=fminf(mnx,__shfl_down(mnx,off)); mxx=fmaxf(mxx,__shfl_down(mxx,off));
    mny=fminf(mny,__shfl_down(mny,off)); mxy=fmaxf(mxy,__shfl_down(mxy,off));
    mnz=fminf(mnz,__shfl_down(mnz,off)); mxz=fmaxf(mxz,__shfl_down(mxz,off));
  }
  if (lane == 0){ r6[wv][0]=mnx; r6[wv][1]=mxx; r6[wv][2]=mny; r6[wv][3]=mxy; r6[wv][4]=mnz; r6[wv][5]=mxz; }
  #pragma unroll
  for (int j = 0; j < 4; ++j) hist[t + j*1024] = 0;
  __syncthreads();
  if (t == 0){
    float a0=r6[0][0], a1=r6[0][1], a2=r6[0][2], a3=r6[0][3], a4=r6[0][4], a5=r6[0][5];
    for (int i = 1; i < 16; ++i){
      a0=fminf(a0,r6[i][0]); a1=fmaxf(a1,r6[i][1]);
      a2=fminf(a2,r6[i][2]); a3=fmaxf(a3,r6[i][3]);
      a4=fminf(a4,r6[i][4]); a5=fmaxf(a5,r6[i][5]);
    }
    bounds[0]=a0; bounds[1]=a1; bounds[2]=a2; bounds[3]=a3; bounds[4]=a4; bounds[5]=a5;
  }
  __syncthreads();
  const float bx0=bounds[0], by0=bounds[2], bz0=bounds[4];
  const float sxm = 16.0f / fmaxf(bounds[1]-bx0, 1e-9f);
  const float sym = 16.0f / fmaxf(bounds[3]-by0, 1e-9f);
  const float szm = 16.0f / fmaxf(bounds[5]-bz0, 1e-9f);
  unsigned keys[8];
  #pragma unroll
  for (int j = 0; j < 8; ++j){
    int cx = (int)((p[j].x - bx0)*sxm); cx = cx<0?0:(cx>15?15:cx);
    int cy = (int)((p[j].y - by0)*sym); cy = cy<0?0:(cy>15?15:cy);
    int cz = (int)((p[j].z - bz0)*szm); cz = cz<0?0:(cz>15?15:cz);
    unsigned k = (spread3((unsigned)cx)<<2) | (spread3((unsigned)cy)<<1) | spread3((unsigned)cz);
    keys[j] = k;
    atomicAdd(&hist[k], 1u);
  }
  __syncthreads();
  unsigned h0=hist[t*4+0], h1=hist[t*4+1], h2=hist[t*4+2], h3=hist[t*4+3];
  unsigned s = h0+h1+h2+h3;
  unsigned pr = s;
  #pragma unroll
  for (int off = 1; off < 64; off <<= 1){ unsigned v = (unsigned)__shfl_up((int)pr, off); if (lane >= off) pr += v; }
  if (lane == 63) wsum[wv] = pr;
  __syncthreads();
  if (t == 0){ unsigned run = 0; for (int i = 0; i < 16; ++i){ unsigned tmp = wsum[i]; wsum[i] = run; run += tmp; } }
  __syncthreads();
  unsigned excl = pr - s + wsum[wv];
  __syncthreads();
  hist[t*4+0]=excl; excl+=h0; hist[t*4+1]=excl; excl+=h1; hist[t*4+2]=excl; excl+=h2; hist[t*4+3]=excl;
  __syncthreads();
  #pragma unroll
  for (int j = 0; j < 8; ++j){
    unsigned pos = atomicAdd(&hist[keys[j]], 1u);
    psort[base + pos] = make_float4(p[j].x, p[j].y, p[j].z, __uint_as_float((unsigned)(t + j*1024)));
  }
}

// ---------------- FPS with EXACT wave-granular bucket skipping, 1 block per batch
// Thread t owns 16 CONSECUTIVE Morton-sorted points (named v2f regs); wave w owns
// 1024 contiguous sorted points. Per-iter cheap test (no sqrt): skip the whole
// wave when ballot shows no bucket can change (dc2 > (rr+sqrt(bmax))^2 with
// conservative fp32 margins) -> lane63 republishes its cached 64-bit key, which
// is bit-identical to a full recompute (md provably unchanged). Key =
// (md_bits<<26) | ((8191-orig)<<13) | sortedpos  -> exact reference tie-breaks.
#define RED8(op, a) op(op(op(a##0,a##1),op(a##2,a##3)),op(op(a##4,a##5),op(a##6,a##7)))
#define FPS_LOAD(k) { \
    int i0 = t*16 + 2*(k), i1 = i0 + 1; \
    float4 a0 = psort[base + i0], a1 = psort[base + i1]; \
    stab[i0] = a0; stab[i1] = a1; \
    px##k=(v2f){a0.x,a1.x}; py##k=(v2f){a0.y,a1.y}; pz##k=(v2f){a0.z,a1.z}; \
    md##k=(v2f){1e10f,1e10f}; \
    lo##k##a = ((8191u - __float_as_uint(a0.w)) << 13) | (unsigned)i0; \
    lo##k##b = ((8191u - __float_as_uint(a1.w)) << 13) | (unsigned)i1; }
#define FPS_UPD(k) { v2f dx=px##k-lx, dy=py##k-ly, dz=pz##k-lz; \
    v2f d=dx*dx+dy*dy+dz*dz; md##k=__builtin_elementwise_min(md##k,d); }
#define FPS_PICK(k) { \
    if (md##k.x == wmf && lo##k##a > blow) blow = lo##k##a; \
    if (md##k.y == wmf && lo##k##b > blow) blow = lo##k##b; }
#define R2M(k) { v2f dx=px##k-ccx, dy=py##k-ccy, dz=pz##k-ccz; \
    v2f r2=dx*dx+dy*dy+dz*dz; r2m=fmaxf(r2m,fmaxf(r2.x,r2.y)); }
#define DPPMAXF(CTRL) { int mo = __builtin_amdgcn_update_dpp(0, __float_as_int(wm), (CTRL), 0xf, 0xf, true); \
    wm = fmaxf(wm, __int_as_float(mo)); }
#define DPPMAXU(CTRL) { int mo = __builtin_amdgcn_update_dpp(0, (int)blow, (CTRL), 0xf, 0xf, true); \
    blow = (blow > (unsigned)mo) ? blow : (unsigned)mo; }

__global__ __launch_bounds__(512, 1) void fps_kernel(const float4* __restrict__ psort,
                                                     const float4* __restrict__ mxyz,
                                                     int* __restrict__ merged){
#pragma clang fp contract(off)
  extern __shared__ float4 stab[];            // 8192 float4 = 128 KB dynamic LDS (sorted coords + orig)
  __shared__ unsigned long long wkey[2][8];
  const int t = threadIdx.x;
  const int b = blockIdx.x;
  const int base = b * N;
  v2f px0,px1,px2,px3,px4,px5,px6,px7;
  v2f py0,py1,py2,py3,py4,py5,py6,py7;
  v2f pz0,pz1,pz2,pz3,pz4,pz5,pz6,pz7;
  v2f md0,md1,md2,md3,md4,md5,md6,md7;
  unsigned lo0a,lo0b,lo1a,lo1b,lo2a,lo2b,lo3a,lo3b,lo4a,lo4b,lo5a,lo5b,lo6a,lo6b,lo7a,lo7b;
  FPS_LOAD(0) FPS_LOAD(1) FPS_LOAD(2) FPS_LOAD(3)
  FPS_LOAD(4) FPS_LOAD(5) FPS_LOAD(6) FPS_LOAD(7)
  // bucket center + conservative radius
  v2f mn2 = RED8(__builtin_elementwise_min, px);
  v2f mx2 = RED8(__builtin_elementwise_max, px);
  const float ccx = 0.5f*(fminf(mn2.x,mn2.y) + fmaxf(mx2.x,mx2.y));
  mn2 = RED8(__builtin_elementwise_min, py);
  mx2 = RED8(__builtin_elementwise_max, py);
  const float ccy = 0.5f*(fminf(mn2.x,mn2.y) + fmaxf(mx2.x,mx2.y));
  mn2 = RED8(__builtin_elementwise_min, pz);
  mx2 = RED8(__builtin_elementwise_max, pz);
  const float ccz = 0.5f*(fminf(mn2.x,mn2.y) + fmaxf(mx2.x,mx2.y));
  float r2m = 0.0f;
  R2M(0) R2M(1) R2M(2) R2M(3) R2M(4) R2M(5) R2M(6) R2M(7)
  const float rr = sqrtf(r2m) * 1.00001f + 1e-9f;
  float rad2 = 3e38f;                          // forces active until first update
  unsigned long long ckey = 0ull;
  if (t == 0) merged[b*2048 + 1024] = 0;       // first fps output is index 0
  __syncthreads();
  float4 w0 = mxyz[base];                      // masked coords of orig point 0
  float lx = w0.x, ly = w0.y, lz = w0.z;
  for (int it = 0; it < 1023; ++it){
    float dxc = ccx-lx, dyc = ccy-ly, dzc = ccz-lz;
    float dc2 = dxc*dxc + dyc*dyc + dzc*dzc;
    bool active = !(dc2 * 0.99999f > rad2);
    if (__ballot(active)){
      FPS_UPD(0) FPS_UPD(1) FPS_UPD(2) FPS_UPD(3)
      FPS_UPD(4) FPS_UPD(5) FPS_UPD(6) FPS_UPD(7)
      v2f vm2 = RED8(__builtin_elementwise_max, md);
      const float bestv = fmaxf(vm2.x, vm2.y);
      float wm = bestv;
      DPPMAXF(0x111) DPPMAXF(0x112) DPPMAXF(0x114) DPPMAXF(0x118)
      DPPMAXF(0x142) DPPMAXF(0x143)            // lane 63 holds wave max
      const float wmf = __int_as_float(__builtin_amdgcn_readlane(__float_as_int(wm), 63));
      unsigned blow = 0u;
      FPS_PICK(0) FPS_PICK(1) FPS_PICK(2) FPS_PICK(3)
      FPS_PICK(4) FPS_PICK(5) FPS_PICK(6) FPS_PICK(7)
      DPPMAXU(0x111) DPPMAXU(0x112) DPPMAXU(0x114) DPPMAXU(0x118)
      DPPMAXU(0x142) DPPMAXU(0x143)            // lane 63: max blow among wmf-holders
      if ((t & 63) == 63)
        ckey = ((unsigned long long)__float_as_uint(wmf) << 26) | (unsigned long long)blow;
      // refresh conservative skip radius (bmax == bestv)
      const float rad = rr + sqrtf(bestv) * 1.00001f + 1e-9f;
      rad2 = rad * rad * 1.00001f + 1e-9f;
    }
    if ((t & 63) == 63) wkey[it & 1][t >> 6] = ckey;
    __syncthreads();
    const unsigned long long* wk = wkey[it & 1];
    unsigned long long k = wk[0];
    #pragma unroll
    for (int i2 = 1; i2 < 8; ++i2){ unsigned long long o = wk[i2]; if (o > k) k = o; }
    const int spos = (int)(k & 0x1FFFull);
    const int orig = 8191 - (int)((k >> 13) & 0x1FFFull);
    if (t == 0) merged[b*2048 + 1024 + it + 1] = orig;
    float4 wv = stab[spos];                    // uniform spos -> broadcast ds_read_b128
    lx = wv.x; ly = wv.y; lz = wv.z;
  }
}

// ---------------- gather outputs: coords + merged-as-float
__global__ void finalize_kernel(const float* __restrict__ xyz, const int* __restrict__ merged,
                                float* __restrict__ out){
  int i = blockIdx.x*256 + threadIdx.x;
  if (i < BATCH*2048){
    int b = i >> 11;
    int idx = merged[i];
    out[12288 + i] = (float)idx;
    const float* p = xyz + (size_t)(b*N + idx)*3;
    out[i*3+0] = p[0]; out[i*3+1] = p[1]; out[i*3+2] = p[2];
  }
}

extern "C" void kernel_launch(void* const* d_in, const int* in_sizes, int n_in,
                              void* d_out, int out_size, void* d_ws, size_t ws_size,
                              hipStream_t stream){
  const float* xyz  = (const float*)d_in[0];
  const float* feat = (const float*)d_in[1];
  const float* w1   = (const float*)d_in[2];
  const float* b1   = (const float*)d_in[3];
  const float* w2   = (const float*)d_in[4];
  const float* b2   = (const float*)d_in[5];
  float* out = (float*)d_out;
  char* ws = (char*)d_ws;
  float*  Q      = (float*) (ws);                  // 16384*128 f32 = 8 MB
  int*    cand   = (int*)   (ws + 8388608);        // 16384*64  i32 = 4 MB
  float*  xs     = (float*) (ws + 12582912);
  float*  ysv    = (float*) (ws + 12648448);
  float*  zsv    = (float*) (ws + 12713984);
  float*  sq     = (float*) (ws + 12779520);
  float*  curv   = (float*) (ws + 12845056);
  float*  fv     = (float*) (ws + 12910592);
  float*  imp    = (float*) (ws + 12976128);
  int*    merged = (int*)   (ws + 13041664);       // 4096 i32
  float*  farval = (float*) (ws + 13058048);       // 1 f32 (+pad)
  float4* mxyz   = (float4*)(ws + 13058112);       // 16384 float4 = 256 KB (16B aligned)
  float4* psort  = (float4*)(ws + 13320256);       // 16384 float4 = 256 KB

  aux_kernel<<<64, 256, 0, stream>>>(xyz, xs, ysv, zsv, sq, mxyz);
  farval_kernel<<<1, 256, 0, stream>>>(xyz, farval);
  q_kernel<<<1024, 128, 0, stream>>>(xyz, feat, w1, Q);
  knn_kernel<<<512, 512, 0, stream>>>(xs, ysv, zsv, sq, cand);
  score_kernel<<<4096, 256, 0, stream>>>(xyz, feat, Q, b1, w2, b2, cand, curv, fv);
  stats_kernel<<<2, 1024, 0, stream>>>(curv, fv, imp);
  topk_kernel<<<2, 1024, 0, stream>>>(imp, merged, mxyz, farval);
  sort_kernel<<<2, 1024, 0, stream>>>(mxyz, psort);
  fps_kernel<<<2, 512, 131072, stream>>>(psort, mxyz, merged);
  finalize_kernel<<<16, 256, 0, stream>>>(xyz, merged, out);
}

// Round 10
// 1609.596 us; speedup vs baseline: 1.1731x; 1.1731x over previous
//
#include <hip/hip_runtime.h>
#include <hip/hip_bf16.h>
#include <math.h>

#define N 8192
#define BATCH 2
#define NROWS (BATCH*N)

typedef float v2f __attribute__((ext_vector_type(2)));

static __device__ __forceinline__ float fsubr(float a, float b){ return __fadd_rn(a, -b); }
static __device__ __forceinline__ unsigned okey(float f){
  unsigned u = __float_as_uint(f);
  return (u & 0x80000000u) ? ~u : (u | 0x80000000u);
}

// ---------------- aux: transpose xyz + |p|^2 + masked-coord float4 image (pre-mask copy)
__global__ void aux_kernel(const float* __restrict__ xyz, float* __restrict__ xs, float* __restrict__ ys,
                           float* __restrict__ zs, float* __restrict__ sq, float4* __restrict__ mxyz){
  int i = blockIdx.x*256 + threadIdx.x;
  if (i < NROWS){
    float x = xyz[i*3+0], y = xyz[i*3+1], z = xyz[i*3+2];
    xs[i]=x; ys[i]=y; zs[i]=z;
    sq[i] = __fadd_rn(__fadd_rn(__fmul_rn(x,x),__fmul_rn(y,y)),__fmul_rn(z,z));
    mxyz[i] = make_float4(x, y, z, 0.0f);
  }
}

// ---------------- far_val = max(xyz) + 1.0f
__global__ void farval_kernel(const float* __restrict__ xyz, float* __restrict__ farval){
  __shared__ float lm[4];
  float m = -1e30f;
  for (int i = threadIdx.x; i < NROWS*3; i += 256) m = fmaxf(m, xyz[i]);
  for (int off = 32; off; off >>= 1) m = fmaxf(m, __shfl_down(m, off));
  if ((threadIdx.x & 63) == 0) lm[threadIdx.x >> 6] = m;
  __syncthreads();
  if (threadIdx.x == 0){
    float r = fmaxf(fmaxf(lm[0],lm[1]), fmaxf(lm[2],lm[3]));
    farval[0] = __fadd_rn(r, 1.0f);
  }
}

// ---------------- Q = xyz @ w1[:3] + feat @ w1[3:]  (per global row, 128 cols)
__global__ __launch_bounds__(128) void q_kernel(const float* __restrict__ xyz, const float* __restrict__ feat,
                                                const float* __restrict__ w1, float* __restrict__ Q){
  __shared__ float sx[16][3];
  __shared__ float sf[16][64];
  const int t = threadIdx.x;
  const int row0 = blockIdx.x * 16;
  for (int j = t; j < 1024; j += 128) sf[j>>6][j&63] = feat[(size_t)row0*64 + j];
  if (t < 48) sx[t/3][t%3] = xyz[(size_t)row0*3 + t];
  __syncthreads();
  float acc[16];
  #pragma unroll
  for (int r = 0; r < 16; ++r) acc[r] = 0.0f;
  for (int c = 0; c < 3; ++c){
    float wv = w1[c*128 + t];
    #pragma unroll
    for (int r = 0; r < 16; ++r) acc[r] = fmaf(sx[r][c], wv, acc[r]);
  }
  for (int c = 0; c < 64; ++c){
    float wv = w1[(3+c)*128 + t];
    #pragma unroll
    for (int r = 0; r < 16; ++r) acc[r] = fmaf(sf[r][c], wv, acc[r]);
  }
  #pragma unroll
  for (int r = 0; r < 16; ++r) Q[(size_t)(row0+r)*128 + t] = acc[r];
}

// ---------------- KNN: per row, exact 65 smallest (d2, idx), drop rank0 (self), store 64 cand
#define BINBASE 0xBA00
__global__ __launch_bounds__(512) void knn_kernel(const float* __restrict__ xs, const float* __restrict__ ys,
                                                  const float* __restrict__ zs, const float* __restrict__ sq,
                                                  int* __restrict__ cand){
#pragma clang fp contract(off)
  __shared__ unsigned fk[N];
  __shared__ unsigned hist[2048];
  __shared__ unsigned long long win[1024];
  __shared__ int scal[8];
  const int t = threadIdx.x;
  const int base_row = blockIdx.x * 32;           // 512 blocks x 32 rows
  const int b = base_row >> 13;
  const int n0 = base_row & (N-1);
  const int pbase = b * N;
  v2f px[8], py[8], pz[8], ps[8];
  #pragma unroll
  for (int k = 0; k < 8; ++k){
    int i0 = t + (2*k)*512, i1 = t + (2*k+1)*512;
    px[k].x = xs[pbase+i0]; px[k].y = xs[pbase+i1];
    py[k].x = ys[pbase+i0]; py[k].y = ys[pbase+i1];
    pz[k].x = zs[pbase+i0]; pz[k].y = zs[pbase+i1];
    ps[k].x = sq[pbase+i0]; ps[k].y = sq[pbase+i1];
  }
  for (int r = 0; r < 32; ++r){
    const int n = n0 + r;
    const float qx = xs[pbase+n], qy = ys[pbase+n], qz = zs[pbase+n], qs = sq[pbase+n];
    #pragma unroll
    for (int j = 0; j < 4; ++j) hist[t + j*512] = 0;
    __syncthreads();
    #pragma unroll
    for (int k = 0; k < 8; ++k){
      v2f dot = px[k]*qx + py[k]*qy + pz[k]*qz;       // ((mul+mul)+mul), rn, packable
      v2f dd  = (qs + ps[k]) - 2.0f*dot;              // 2*dot exact; one rounding on sub
      unsigned u0 = okey(dd.x), u1 = okey(dd.y);
      fk[t + (2*k)*512] = u0;
      fk[t + (2*k+1)*512] = u1;
      int bin0 = (int)(u0 >> 16) - BINBASE; bin0 = bin0 < 0 ? 0 : (bin0 > 2047 ? 2047 : bin0);
      int bin1 = (int)(u1 >> 16) - BINBASE; bin1 = bin1 < 0 ? 0 : (bin1 > 2047 ? 2047 : bin1);
      atomicAdd(&hist[bin0], 1u);
      atomicAdd(&hist[bin1], 1u);
    }
    __syncthreads();
    if (t < 64){
      unsigned s = 0;
      for (int k2 = 0; k2 < 32; ++k2) s += hist[t*32 + ((k2 + t) & 31)];   // rotated: conflict-free
      unsigned p = s;
      for (int off = 1; off < 64; off <<= 1){ unsigned v = (unsigned)__shfl_up((int)p, off); if (t >= off) p += v; }
      int excl = (int)(p - s);
      if (excl < 65 && (int)p >= 65){ scal[0] = t; scal[1] = excl; }
    }
    __syncthreads();
    {
      int g = scal[0];
      if (t < 32){
        unsigned s = hist[g*32 + t];
        unsigned p = s;
        for (int off = 1; off < 32; off <<= 1){ unsigned v = (unsigned)__shfl_up((int)p, off); if (t >= off) p += v; }
        int before = scal[1] + (int)(p - s);
        if (before < 65 && scal[1] + (int)p >= 65) scal[2] = g*32 + t;
      }
    }
    if (t == 0) scal[3] = 0;
    __syncthreads();
    int B1 = scal[2];
    unsigned limit = (B1 >= 2047) ? 0xFFFFFFFFu : ((unsigned)(BINBASE + B1 + 1) << 16);
    #pragma unroll
    for (int j = 0; j < 16; ++j){
      int i = t + j*512;
      unsigned u = fk[i];
      if (u < limit){
        int p = atomicAdd(&scal[3], 1);
        if (p < 1024) win[p] = ((unsigned long long)u << 32) | (unsigned)i;
      }
    }
    __syncthreads();
    int m = scal[3]; if (m > 1024) m = 1024;
    for (int e = t; e < m; e += 512){
      unsigned long long me = win[e];
      int rk = 0;
      for (int j2 = 0; j2 < m; ++j2) rk += (win[j2] < me) ? 1 : 0;
      if (rk >= 1 && rk < 65) cand[(size_t)(pbase + n)*64 + (rk-1)] = (int)(me & 0xFFFFFFFFull);
    }
    __syncthreads();
  }
}

// ---------------- scores + top16 + covariance/eigen curvature + feat_var  (one wave per row)
__global__ __launch_bounds__(256) void score_kernel(const float* __restrict__ xyz, const float* __restrict__ feat,
                                                    const float* __restrict__ Q, const float* __restrict__ b1,
                                                    const float* __restrict__ w2, const float* __restrict__ b2,
                                                    const int* __restrict__ cand,
                                                    float* __restrict__ curv, float* __restrict__ fv){
  __shared__ float4 sb14[32], sw24[32];
  __shared__ int ssel[4][16];
  __shared__ float sdx[4][16], sdy[4][16], sdz[4][16], snrm[4][16];
  const int t = threadIdx.x;
  if (t < 32) sb14[t] = ((const float4*)b1)[t];
  else if (t < 64) sw24[t-32] = ((const float4*)w2)[t-32];
  __syncthreads();
  const int w = t >> 6, lane = t & 63;
  const int row = blockIdx.x*4 + w;               // global row
  const int b = row >> 13;
  const int pbase = b * N;
  const int n = row & (N-1);
  const int ck = cand[(size_t)row*64 + lane];
  const float4* Qn4 = (const float4*)(Q + (size_t)row * 128);
  const float4* Qc4 = (const float4*)(Q + (size_t)(pbase + ck) * 128);
  const float ks = 0.70710678118654752440f;
  float acc = 0.0f;
  for (int c = 0; c < 32; ++c){
    float4 qc = Qc4[c], qn = Qn4[c], bb = sb14[c], ww = sw24[c];
    float p0 = (qc.x - qn.x) + bb.x;
    float g0 = 0.5f * p0 * (1.0f + erff(p0 * ks));
    acc += g0 * ww.x;
    float p1 = (qc.y - qn.y) + bb.y;
    float g1 = 0.5f * p1 * (1.0f + erff(p1 * ks));
    acc += g1 * ww.y;
    float p2 = (qc.z - qn.z) + bb.z;
    float g2 = 0.5f * p2 * (1.0f + erff(p2 * ks));
    acc += g2 * ww.z;
    float p3 = (qc.w - qn.w) + bb.w;
    float g3 = 0.5f * p3 * (1.0f + erff(p3 * ks));
    acc += g3 * ww.w;
  }
  float score = acc + b2[0];
  unsigned key = okey(score);
  int rk = 0;
  for (int j = 0; j < 64; ++j){
    unsigned kj = (unsigned)__shfl((int)key, j);
    rk += (kj > key || (kj == key && j < lane)) ? 1 : 0;
  }
  float cx = xyz[(size_t)(pbase+ck)*3+0], cy = xyz[(size_t)(pbase+ck)*3+1], cz = xyz[(size_t)(pbase+ck)*3+2];
  float qxv = xyz[(size_t)(pbase+n)*3+0], qyv = xyz[(size_t)(pbase+n)*3+1], qzv = xyz[(size_t)(pbase+n)*3+2];
  if (rk < 16){
    ssel[w][rk] = ck;
    sdx[w][rk] = fsubr(cx, qxv);
    sdy[w][rk] = fsubr(cy, qyv);
    sdz[w][rk] = fsubr(cz, qzv);
  }
  __syncthreads();
  if (lane < 16){
    int si = ssel[w][lane];
    const float4* fc4 = (const float4*)(feat + (size_t)(pbase+si)*64);
    const float4* fn4 = (const float4*)(feat + (size_t)(pbase+n)*64);
    double s = 0.0;
    for (int c = 0; c < 16; ++c){
      float4 a = fc4[c], bq = fn4[c];
      float d0 = fsubr(a.x, bq.x); s += (double)d0 * (double)d0;
      float d1 = fsubr(a.y, bq.y); s += (double)d1 * (double)d1;
      float d2 = fsubr(a.z, bq.z); s += (double)d2 * (double)d2;
      float d3 = fsubr(a.w, bq.w); s += (double)d3 * (double)d3;
    }
    snrm[w][lane] = sqrtf((float)s);
  }
  __syncthreads();
  if (lane == 0){
    double cxx=0, cxy=0, cxz=0, cyy=0, cyz=0, czz=0;
    for (int k2 = 0; k2 < 16; ++k2){
      double dx = (double)sdx[w][k2], dy = (double)sdy[w][k2], dz = (double)sdz[w][k2];
      cxx += dx*dx; cxy += dx*dy; cxz += dx*dz; cyy += dy*dy; cyz += dy*dz; czz += dz*dz;
    }
    float fxx = (float)(cxx/16.0), fxy = (float)(cxy/16.0), fxz = (float)(cxz/16.0);
    float fyy = (float)(cyy/16.0), fyz = (float)(cyz/16.0), fzz = (float)(czz/16.0);
    double a = fxx, bbv = fyy, c = fzz, d = fxy, e = fyz, f = fxz;
    double p1 = d*d + f*f + e*e;
    double e0, e1, e2v;
    if (p1 == 0.0){ e0 = a; e1 = bbv; e2v = c; }
    else {
      double q = (a + bbv + c) / 3.0;
      double aa = a - q, bq = bbv - q, cc = c - q;
      double p2 = aa*aa + bq*bq + cc*cc + 2.0*p1;
      double p = sqrt(p2 / 6.0);
      double inv = 1.0 / p;
      double bxx = aa*inv, byy = bq*inv, bzz = cc*inv, bxy = d*inv, bxz = f*inv, byz = e*inv;
      double detB = bxx*(byy*bzz - byz*byz) - bxy*(bxy*bzz - byz*bxz) + bxz*(bxy*byz - byy*bxz);
      double rr = 0.5 * detB;
      rr = fmin(1.0, fmax(-1.0, rr));
      double phi = acos(rr) / 3.0;
      e0 = q + 2.0*p*cos(phi);
      e2v = q + 2.0*p*cos(phi + 2.0943951023931953);
      e1 = 3.0*q - e0 - e2v;
    }
    double s0 = fabs(e0), s1 = fabs(e1), s2d = fabs(e2v), tt;
    if (s0 < s1){ tt=s0; s0=s1; s1=tt; }
    if (s1 < s2d){ tt=s1; s1=s2d; s2d=tt; }
    if (s0 < s1){ tt=s0; s0=s1; s1=tt; }
    float sv0 = (float)s0, sv1 = (float)s1, sv2 = (float)s2d;
    float l2f = __fmul_rn(sv0,sv0), l1f = __fmul_rn(sv1,sv1), l0f = __fmul_rn(sv2,sv2);
    float den = __fadd_rn(__fadd_rn(__fadd_rn(l0f, l1f), l2f), 1e-8f);
    curv[row] = l0f / den;
    double fs = 0.0;
    for (int k2 = 0; k2 < 16; ++k2) fs += (double)snrm[w][k2];
    fv[row] = (float)(fs / 16.0);
  }
}

// ---------------- per-batch znorm + importance
static __device__ __forceinline__ double blk_sum(double v, double* lds, int t){
  for (int off = 32; off; off >>= 1) v += __shfl_down(v, off);
  int w = t >> 6, lane = t & 63;
  if (lane == 0) lds[w] = v;
  __syncthreads();
  double r = (t < 16) ? lds[t] : 0.0;
  if (t < 64){ for (int off = 8; off; off >>= 1) r += __shfl_down(r, off); }
  if (t == 0) lds[0] = r;
  __syncthreads();
  double out = lds[0];
  __syncthreads();
  return out;
}

__global__ __launch_bounds__(1024) void stats_kernel(const float* __restrict__ curv, const float* __restrict__ fv,
                                                     float* __restrict__ imp){
  __shared__ double lds[16];
  const int t = threadIdx.x;
  const int base = blockIdx.x * N;
  double sc = 0, sf = 0;
  for (int j = 0; j < 8; ++j){ int i = t + j*1024; sc += (double)curv[base+i]; sf += (double)fv[base+i]; }
  double Sc = blk_sum(sc, lds, t);
  double Sf = blk_sum(sf, lds, t);
  double mc = Sc/8192.0, mf = Sf/8192.0;
  double vc = 0, vf = 0;
  for (int j = 0; j < 8; ++j){ int i = t + j*1024;
    double d1 = (double)curv[base+i] - mc; vc += d1*d1;
    double d2 = (double)fv[base+i]  - mf; vf += d2*d2; }
  double Vc = blk_sum(vc, lds, t);
  double Vf = blk_sum(vf, lds, t);
  float mcf = (float)mc, mff = (float)mf;
  float dc = __fadd_rn((float)sqrt(Vc/8191.0), 1e-8f);
  float df = __fadd_rn((float)sqrt(Vf/8191.0), 1e-8f);
  for (int j = 0; j < 8; ++j){ int i = t + j*1024;
    float zc = fsubr(curv[base+i], mcf) / dc;
    float zf = fsubr(fv[base+i],  mff) / df;
    imp[base+i] = __fadd_rn(zc, __fmul_rn(0.5f, zf));
  }
}

// ---------------- top-1024 importance (ordered) -> curv_idx + masked-coord scatter (far)
// R10: fine binning (base 0x3E00, covers imp in [~0.03, 16], monotone in inverted key)
// -> cutoff-bin population collapses, m ~= 1024+eps (was up to ~2048: 4x scan cost +
// latent win-overflow risk).
#define TBINBASE 0x3E00
__global__ __launch_bounds__(1024) void topk_kernel(const float* __restrict__ imp, int* __restrict__ merged,
                                                    float4* __restrict__ mxyz, const float* __restrict__ farval){
  __shared__ unsigned dk[N];
  __shared__ unsigned hist[2048];
  __shared__ unsigned long long win[2048];
  __shared__ int scal[8];
  const int t = threadIdx.x;
  const int b = blockIdx.x;
  const int base = b * N;
  #pragma unroll
  for (int j = 0; j < 2; ++j) hist[t + j*1024] = 0;
  if (t == 0) scal[3] = 0;
  __syncthreads();
  for (int j = 0; j < 8; ++j){
    int i = t + j*1024;
    unsigned u = ~okey(imp[base+i]);   // ascending = descending importance
    dk[i] = u;
    int bin = (int)(u >> 16) - TBINBASE; bin = bin < 0 ? 0 : (bin > 2047 ? 2047 : bin);
    atomicAdd(&hist[bin], 1u);
  }
  __syncthreads();
  if (t < 64){
    unsigned s = 0;
    for (int k2 = 0; k2 < 32; ++k2) s += hist[t*32 + ((k2 + t) & 31)];
    unsigned p = s;
    for (int off = 1; off < 64; off <<= 1){ unsigned v = (unsigned)__shfl_up((int)p, off); if (t >= off) p += v; }
    int excl = (int)(p - s);
    if (excl < 1024 && (int)p >= 1024){ scal[0] = t; scal[1] = excl; }
  }
  __syncthreads();
  {
    int g = scal[0];
    if (t < 32){
      unsigned s = hist[g*32 + t];
      unsigned p = s;
      for (int off = 1; off < 32; off <<= 1){ unsigned v = (unsigned)__shfl_up((int)p, off); if (t >= off) p += v; }
      int before = scal[1] + (int)(p - s);
      if (before < 1024 && scal[1] + (int)p >= 1024) scal[2] = g*32 + t;
    }
  }
  __syncthreads();
  int B1 = scal[2];
  unsigned limit = (B1 >= 2047) ? 0xFFFFFFFFu : ((unsigned)(TBINBASE + B1 + 1) << 16);
  for (int j = 0; j < 8; ++j){
    int i = t + j*1024;
    unsigned u = dk[i];
    if (u < limit){
      int p = atomicAdd(&scal[3], 1);
      if (p < 2048) win[p] = ((unsigned long long)u << 13) | (unsigned)i;
    }
  }
  __syncthreads();
  int m = scal[3]; if (m > 2048) m = 2048;
  const float far = farval[0];
  for (int e = t; e < m; e += 1024){
    unsigned long long me = win[e];
    int rk = 0;
    for (int j2 = 0; j2 < m; ++j2) rk += (win[j2] < me) ? 1 : 0;
    if (rk < 1024){
      int idx = (int)(me & 0x1FFFull);
      merged[b*2048 + rk] = idx;
      mxyz[base + idx] = make_float4(far, far, far, 0.0f);
    }
  }
}

// ---------------- FPS (bit-exact fp32 chain), 1 block per batch
// R10: exact revert to the R6 kernel (best measured: 891 us). Evidence from R4/R7/R8/R9:
// fps is serial-chain-bound (~2100 cyc/iter); VALU cuts are neutral, chain additions
// (prune tests, ballot) regress. R6 structure: 512 thr x 16 pts arrays, DPP64 max
// reduce, lane63 plain ds_write into parity slot banks, single barrier, winner coords
// via broadcast ds_read_b128 from a 128 KB dynamic-LDS coord table.
#define DPP_MAX64(CTRL) { \
    int nlo = __builtin_amdgcn_update_dpp(0, klo, (CTRL), 0xf, 0xf, true); \
    int nhi = __builtin_amdgcn_update_dpp(0, khi, (CTRL), 0xf, 0xf, true); \
    unsigned long long nk = ((unsigned long long)(unsigned)nhi << 32) | (unsigned)nlo; \
    unsigned long long ck = ((unsigned long long)(unsigned)khi << 32) | (unsigned)klo; \
    if (nk > ck){ klo = nlo; khi = nhi; } \
  }

__global__ __launch_bounds__(512, 2) void fps_kernel(const float4* __restrict__ mxyz, int* __restrict__ merged){
  extern __shared__ float4 stab[];            // 8192 float4 = 128 KB dynamic LDS
  __shared__ unsigned long long wkey[2][8];
  const int t = threadIdx.x;
  const int b = blockIdx.x;
  const int base = b * N;
  float px[16], py[16], pz[16], md[16];
  #pragma unroll
  for (int j = 0; j < 16; ++j){
    int i = t + j*512;
    float4 p = mxyz[base + i];
    px[j] = p.x; py[j] = p.y; pz[j] = p.z; md[j] = 1e10f;
    stab[i] = p;
  }
  if (t == 0) merged[b*2048 + 1024] = 0;      // first fps output is index 0
  __syncthreads();
  float4 w0 = stab[0];
  float lx = w0.x, ly = w0.y, lz = w0.z;
  for (int it = 0; it < 1023; ++it){
    float bestv = -1.0f; unsigned blow = 0u;
    #pragma unroll
    for (int j = 0; j < 16; ++j){
      float dx = fsubr(px[j], lx), dy = fsubr(py[j], ly), dz = fsubr(pz[j], lz);
      float d = __fadd_rn(__fadd_rn(__fmul_rn(dx,dx), __fmul_rn(dy,dy)), __fmul_rn(dz,dz));
      float nm = fminf(md[j], d);
      md[j] = nm;
      if (nm > bestv){ bestv = nm; blow = 8191u - (unsigned)(t + (j<<9)); }  // first-j kept on tie = smallest orig idx
    }
    unsigned long long key = ((unsigned long long)__float_as_uint(bestv) << 13) | (unsigned long long)blow;
    int klo = (int)(unsigned)(key & 0xFFFFFFFFull);
    int khi = (int)(unsigned)(key >> 32);
    DPP_MAX64(0x111)   // row_shr:1
    DPP_MAX64(0x112)   // row_shr:2
    DPP_MAX64(0x114)   // row_shr:4
    DPP_MAX64(0x118)   // row_shr:8
    DPP_MAX64(0x142)   // row_bcast:15
    DPP_MAX64(0x143)   // row_bcast:31  -> lane 63 holds wave max
    if ((t & 63) == 63)
      wkey[it & 1][t >> 6] = ((unsigned long long)(unsigned)khi << 32) | (unsigned)klo;
    __syncthreads();
    const unsigned long long* wk = wkey[it & 1];
    unsigned long long k = wk[0];
    #pragma unroll
    for (int i2 = 1; i2 < 8; ++i2){ unsigned long long o = wk[i2]; if (o > k) k = o; }
    const int idx = 8191 - (int)(k & 0x1FFFull);
    if (t == 0) merged[b*2048 + 1024 + it + 1] = idx;
    float4 wv = stab[idx];                    // uniform idx -> broadcast ds_read_b128
    lx = wv.x; ly = wv.y; lz = wv.z;
  }
}

// ---------------- gather outputs: coords + merged-as-float
__global__ void finalize_kernel(const float* __restrict__ xyz, const int* __restrict__ merged,
                                float* __restrict__ out){
  int i = blockIdx.x*256 + threadIdx.x;
  if (i < BATCH*2048){
    int b = i >> 11;
    int idx = merged[i];
    out[12288 + i] = (float)idx;
    const float* p = xyz + (size_t)(b*N + idx)*3;
    out[i*3+0] = p[0]; out[i*3+1] = p[1]; out[i*3+2] = p[2];
  }
}

extern "C" void kernel_launch(void* const* d_in, const int* in_sizes, int n_in,
                              void* d_out, int out_size, void* d_ws, size_t ws_size,
                              hipStream_t stream){
  const float* xyz  = (const float*)d_in[0];
  const float* feat = (const float*)d_in[1];
  const float* w1   = (const float*)d_in[2];
  const float* b1   = (const float*)d_in[3];
  const float* w2   = (const float*)d_in[4];
  const float* b2   = (const float*)d_in[5];
  float* out = (float*)d_out;
  char* ws = (char*)d_ws;
  float*  Q      = (float*) (ws);                  // 16384*128 f32 = 8 MB
  int*    cand   = (int*)   (ws + 8388608);        // 16384*64  i32 = 4 MB
  float*  xs     = (float*) (ws + 12582912);
  float*  ysv    = (float*) (ws + 12648448);
  float*  zsv    = (float*) (ws + 12713984);
  float*  sq     = (float*) (ws + 12779520);
  float*  curv   = (float*) (ws + 12845056);
  float*  fv     = (float*) (ws + 12910592);
  float*  imp    = (float*) (ws + 12976128);
  int*    merged = (int*)   (ws + 13041664);       // 4096 i32
  float*  farval = (float*) (ws + 13058048);       // 1 f32 (+pad)
  float4* mxyz   = (float4*)(ws + 13058112);       // 16384 float4 = 256 KB (16B aligned)

  aux_kernel<<<64, 256, 0, stream>>>(xyz, xs, ysv, zsv, sq, mxyz);
  farval_kernel<<<1, 256, 0, stream>>>(xyz, farval);
  q_kernel<<<1024, 128, 0, stream>>>(xyz, feat, w1, Q);
  knn_kernel<<<512, 512, 0, stream>>>(xs, ysv, zsv, sq, cand);
  score_kernel<<<4096, 256, 0, stream>>>(xyz, feat, Q, b1, w2, b2, cand, curv, fv);
  stats_kernel<<<2, 1024, 0, stream>>>(curv, fv, imp);
  topk_kernel<<<2, 1024, 0, stream>>>(imp, merged, mxyz, farval);
  fps_kernel<<<2, 512, 131072, stream>>>(mxyz, merged);
  finalize_kernel<<<16, 256, 0, stream>>>(xyz, merged, out);
}